// Round 12
// baseline (113.322 us; speedup 1.0000x reference)
//
#include <hip/hip_runtime.h>
#include <math.h>

// Problem constants: B*T = 32768 rows, C=1, V=256, K=512 codes.
#define NV 256
#define NK 512
#define TSH 4096      // shorts per 16-code tile (16 codes * 256 dims, bf16)
#define SLABR 128     // rows per search block (8 x-tiles of 16)

typedef unsigned short u16;
typedef unsigned int u32;
using short8  = __attribute__((ext_vector_type(8))) short;
using floatx4 = __attribute__((ext_vector_type(4))) float;

// fp32 -> bf16 round-to-nearest-even.
__device__ __forceinline__ u16 f2bf(float f) {
    unsigned int u = __float_as_uint(f);
    u += 0x7fffu + ((u >> 16) & 1u);
    return (u16)(u >> 16);
}
__device__ __forceinline__ floatx4 mfma16(short8 a, short8 b, floatx4 c) {
    return __builtin_amdgcn_mfma_f32_16x16x32_bf16(a, b, c, 0, 0, 0);
}

// Kernel 0: per-code esq(+2.0 bias: distance keys provably positive), bf16
// codebook packed in MFMA order shorts[tile][kc][code][8]; zero hist/counter.
__global__ __launch_bounds__(256) void vq_prepcvt(const float* __restrict__ emb,
                                                  float* __restrict__ esq1,
                                                  u16* __restrict__ ehws,
                                                  int* __restrict__ hist,
                                                  int* __restrict__ counter) {
    const int t = threadIdx.x;
    const int lane = t & 63;
    const int code = blockIdx.x * 4 + (t >> 6);   // one wave per code
    const int nt = code >> 4, c = code & 15;
    const float4 v = *(const float4*)(emb + (size_t)code * NV + lane * 4);
    ushort4 h;
    h.x = f2bf(v.x);
    h.y = f2bf(v.y);
    h.z = f2bf(v.z);
    h.w = f2bf(v.w);
    // dim base = lane*4 -> kchunk8 = lane>>1, j0 = (lane&1)*4
    const size_t base = (size_t)nt * TSH + (size_t)(lane >> 1) * 128 + c * 8 + (lane & 1) * 4;
    *(ushort4*)(ehws + base) = h;
    float s = v.x * v.x + v.y * v.y + v.z * v.z + v.w * v.w;
#pragma unroll
    for (int m = 1; m <= 32; m <<= 1) s += __shfl_xor(s, m, 64);
    if (lane == 0) esq1[code] = s + 2.0f;
    const int g = blockIdx.x * 256 + t;
    if (g < NK) hist[g] = 0;
    if (g == 0) *counter = 0;
}

// Kernel 1: code-stationary nearest-code search, full codebook per block.
// Block = 16 waves; wave w holds code tiles {2w, 2w+1} (32 codes) in
// registers forever. Grid = 256 slabs of 128 rows. x streams through LDS
// (bf16, XOR-swizzled, double-buffered, T14 load-early/write-late).
// Winners are block-local: per-phase fragments go to kall[] in LDS,
// one combine at the end, plain stores to idx_ws. One barrier per phase.
__global__ __launch_bounds__(1024, 4) void vq_search(
    const float* __restrict__ x,
    const u16* __restrict__ ehws,
    const float* __restrict__ esq1,
    u32* __restrict__ idx_ws) {
    __shared__ u16 xl[2][16 * NV];        // 16 KB: double-buffered bf16 x-tile
    __shared__ u32 kall[8][16][16];       // 8 KB: [tau][wave][row] winners

    const int t = threadIdx.x;
    const int wid = t >> 6;               // wave = 0..15 (also: staged row)
    const int lane = t & 63;
    const int lr = lane & 15;
    const int lg = lane >> 4;
    const size_t row0 = (size_t)blockIdx.x * SLABR;

    // ---- stationary B: this wave's 2 code tiles (32 codes) + their esq ----
    const u16* bb0 = ehws + (size_t)(2 * wid) * TSH + lane * 8;
    const u16* bb1 = ehws + (size_t)(2 * wid + 1) * TSH + lane * 8;
    short8 b0[8], b1[8];
#pragma unroll
    for (int ks = 0; ks < 8; ++ks) {
        b0[ks] = *(const short8*)(bb0 + ks * 512);
        b1[ks] = *(const short8*)(bb1 + ks * 512);
    }
    const float evq0 = esq1[(2 * wid) * 16 + lr];       // esq + 2.0
    const float evq1 = esq1[(2 * wid + 1) * 16 + lr];
    const u32 cid0 = (u32)((2 * wid) * 16 + lr);
    const u32 cid1 = (u32)((2 * wid + 1) * 16 + lr);

#define XLOAD(XR, TAU)                                                         \
    XR = *(const float4*)(x + (row0 + (TAU) * 16 + wid) * NV + lane * 4)
#define XWRITE(XR, BUF) do {                                                   \
        u32 lo = (u32)f2bf(XR.x) | ((u32)f2bf(XR.y) << 16);                    \
        u32 hi = (u32)f2bf(XR.z) | ((u32)f2bf(XR.w) << 16);                    \
        int byte = wid * 512 + ((lane * 8) ^ ((wid & 7) << 4));                \
        *(uint2*)((char*)&xl[BUF][0] + byte) = make_uint2(lo, hi);             \
    } while (0)

    float4 xr;
    XLOAD(xr, 0);
    XWRITE(xr, 0);
    __syncthreads();

    // ---- 8 phases over x-tiles ----
#pragma unroll 2
    for (int tau = 0; tau < 8; ++tau) {
        const int buf = tau & 1;
        if (tau < 7) XLOAD(xr, tau + 1);          // issue early (T14)

        floatx4 a0e = {0.f,0.f,0.f,0.f}, a0o = {0.f,0.f,0.f,0.f};
        floatx4 a1e = {0.f,0.f,0.f,0.f}, a1o = {0.f,0.f,0.f,0.f};
#pragma unroll
        for (int ks = 0; ks < 8; ++ks) {
            // A-frag: row lr, dims ks*32+lg*8.. ; same XOR swizzle as write
            int byte = lr * 512 + ((ks * 64 + lg * 16) ^ ((lr & 7) << 4));
            short8 a = *(const short8*)((const char*)&xl[buf][0] + byte);
            if (ks & 1) { a0o = mfma16(a, b0[ks], a0o); a1o = mfma16(a, b1[ks], a1o); }
            else        { a0e = mfma16(a, b0[ks], a0e); a1e = mfma16(a, b1[ks], a1e); }
        }
        u32 rmin[4];
#pragma unroll
        for (int j = 0; j < 4; ++j) {
            // d+2 = (esq+2) - 2*cross > 0 -> raw float bits are monotone
            float d0 = fmaf(-2.0f, a0e[j] + a0o[j], evq0);
            float d1 = fmaf(-2.0f, a1e[j] + a1o[j], evq1);
            u32 k0 = (__float_as_uint(d0) & 0xfffffe00u) | cid0;
            u32 k1 = (__float_as_uint(d1) & 0xfffffe00u) | cid1;
            rmin[j] = min(k0, k1);
        }
        // min over this wave's 16 code-lanes (low 4 lane bits)
#pragma unroll
        for (int j = 0; j < 4; ++j) {
#pragma unroll
            for (int m = 1; m <= 8; m <<= 1) {
                u32 v = (u32)__shfl_xor((int)rmin[j], m, 64);
                rmin[j] = min(rmin[j], v);
            }
        }
        if (lr == 0) {
#pragma unroll
            for (int j = 0; j < 4; ++j) kall[tau][wid][lg * 4 + j] = rmin[j];
        }

        if (tau < 7) XWRITE(xr, buf ^ 1);          // write late (T14)
        __syncthreads();
    }
#undef XLOAD
#undef XWRITE

    // ---- final combine: min across the 16 waves, plain store ----
    if (t < SLABR) {
        u32 v = 0xffffffffu;
#pragma unroll
        for (int w = 0; w < 16; ++w) v = min(v, kall[t >> 4][w][t & 15]);
        idx_ws[row0 + t] = v & 511u;
    }
}

// Kernel 2: epilogue — gather e[idx], straight-through out0, loss sums,
// histogram; fused entropy via last-block election. Grid 2048 x 256
// = 32 waves/CU; 4 rows/wave fully unrolled (independent streams).
__global__ __launch_bounds__(256) void vq_epi(
    const float* __restrict__ x,
    const float* __restrict__ emb,
    const u32* __restrict__ idx_ws,
    int* __restrict__ hist,
    int* __restrict__ counter,
    float* __restrict__ out0,
    float* __restrict__ out1,
    float* __restrict__ out2,
    float* __restrict__ ent,
    int n_rows) {
    __shared__ float sred[256];
    __shared__ int s_last;

    const int t = threadIdx.x;
    const int wid = t >> 6;
    const int lane = t & 63;
    const size_t rbase = ((size_t)blockIdx.x * 4 + wid) * 4;

    int idx[4];
#pragma unroll
    for (int rr = 0; rr < 4; ++rr) idx[rr] = (int)idx_ws[rbase + rr];

    float s[4];
#pragma unroll
    for (int rr = 0; rr < 4; ++rr) {
        const size_t row = rbase + rr;
        const float4 xv = *(const float4*)(x + row * NV + lane * 4);
        const float4 ev = *(const float4*)(emb + (size_t)idx[rr] * NV + lane * 4);
        float4 o;
        o.x = (ev.x - xv.x) + xv.x;
        o.y = (ev.y - xv.y) + xv.y;
        o.z = (ev.z - xv.z) + xv.z;
        o.w = (ev.w - xv.w) + xv.w;
        *(float4*)(out0 + row * NV + lane * 4) = o;
        float d0 = xv.x - ev.x, d1 = xv.y - ev.y, d2 = xv.z - ev.z, d3 = xv.w - ev.w;
        s[rr] = d0 * d0 + d1 * d1 + d2 * d2 + d3 * d3;
    }
#pragma unroll
    for (int rr = 0; rr < 4; ++rr) {
#pragma unroll
        for (int m = 1; m <= 32; m <<= 1) s[rr] += __shfl_xor(s[rr], m, 64);
    }
    if (lane == 0) {
#pragma unroll
        for (int rr = 0; rr < 4; ++rr) {
            out1[rbase + rr] = s[rr];
            out2[rbase + rr] = s[rr];
            atomicAdd(&hist[idx[rr]], 1);
        }
    }
    __syncthreads();
    if (t == 0) {
        __threadfence();
        s_last = (atomicAdd(counter, 1) == (int)gridDim.x - 1);
    }
    __syncthreads();
    if (s_last) {
        const float invn = 1.0f / (float)n_rows;
        float local = 0.0f;
        for (int k = t; k < NK; k += 256) {
            int h = atomicAdd(&hist[k], 0);   // device-coherent read
            if (h > 0) {
                float p = (float)h * invn;
                local += p * logf(p);
            }
        }
        sred[t] = local;
        __syncthreads();
        for (int ss = 128; ss >= 1; ss >>= 1) {
            if (t < ss) sred[t] += sred[t + ss];
            __syncthreads();
        }
        if (t == 0) *ent = -sred[0];
    }
}

extern "C" void kernel_launch(void* const* d_in, const int* in_sizes, int n_in,
                              void* d_out, int out_size, void* d_ws, size_t ws_size,
                              hipStream_t stream) {
    const float* x   = (const float*)d_in[0];   // (B,T,1,256) fp32
    const float* emb = (const float*)d_in[1];   // (1,512,256) fp32

    const int n_rows = in_sizes[0] / NV;        // 32768

    float* out0 = (float*)d_out;
    float* out1 = out0 + (size_t)n_rows * NV;
    float* out2 = out1 + n_rows;
    float* ent  = out2 + n_rows;

    // ws: esq+2 (2KB) | hist (2KB) | counter (16B) | idx_ws (128KB) | bf16 codebook (256KB)
    float* esq1  = (float*)d_ws;
    int* hist    = (int*)(esq1 + NK);
    int* counter = hist + NK;
    u32* idx_ws  = (u32*)(counter + 4);
    u16* ehws    = (u16*)(idx_ws + n_rows);

    vq_prepcvt<<<NK / 4, 256, 0, stream>>>(emb, esq1, ehws, hist, counter);
    vq_search<<<n_rows / SLABR, 1024, 0, stream>>>(x, ehws, esq1, idx_ws);
    vq_epi<<<n_rows / 16, 256, 0, stream>>>(x, emb, idx_ws, hist, counter,
                                            out0, out1, out2, ent, n_rows);
}

// Round 13
// 54.674 us; speedup vs baseline: 2.0727x; 2.0727x over previous
//
#include <hip/hip_runtime.h>
#include <math.h>

// Problem constants: B*T = 32768 rows, C=1, V=256, K=512 codes.
#define NV 256
#define NK 512
#define TSH 4096      // shorts per 16-code tile (16 codes * 256 dims, bf16)
#define SLABR 128     // rows per search block (8 x-tiles of 16)

typedef unsigned short u16;
typedef unsigned int u32;
using short8  = __attribute__((ext_vector_type(8))) short;
using floatx4 = __attribute__((ext_vector_type(4))) float;

// fp32 -> bf16 round-to-nearest-even.
__device__ __forceinline__ u16 f2bf(float f) {
    unsigned int u = __float_as_uint(f);
    u += 0x7fffu + ((u >> 16) & 1u);
    return (u16)(u >> 16);
}
__device__ __forceinline__ floatx4 mfma16(short8 a, short8 b, floatx4 c) {
    return __builtin_amdgcn_mfma_f32_16x16x32_bf16(a, b, c, 0, 0, 0);
}

// Kernel 0: per-code esq(+2.0 bias: distance keys provably positive), bf16
// codebook packed in MFMA order shorts[tile][kc][code][8]; zero hist.
__global__ __launch_bounds__(256) void vq_prepcvt(const float* __restrict__ emb,
                                                  float* __restrict__ esq1,
                                                  u16* __restrict__ ehws,
                                                  int* __restrict__ hist) {
    const int t = threadIdx.x;
    const int lane = t & 63;
    const int code = blockIdx.x * 4 + (t >> 6);   // one wave per code
    const int nt = code >> 4, c = code & 15;
    const float4 v = *(const float4*)(emb + (size_t)code * NV + lane * 4);
    ushort4 h;
    h.x = f2bf(v.x);
    h.y = f2bf(v.y);
    h.z = f2bf(v.z);
    h.w = f2bf(v.w);
    // dim base = lane*4 -> kchunk8 = lane>>1, j0 = (lane&1)*4
    const size_t base = (size_t)nt * TSH + (size_t)(lane >> 1) * 128 + c * 8 + (lane & 1) * 4;
    *(ushort4*)(ehws + base) = h;
    float s = v.x * v.x + v.y * v.y + v.z * v.z + v.w * v.w;
#pragma unroll
    for (int m = 1; m <= 32; m <<= 1) s += __shfl_xor(s, m, 64);
    if (lane == 0) esq1[code] = s + 2.0f;
    const int g = blockIdx.x * 256 + t;
    if (g < NK) hist[g] = 0;
}

// Kernel 1: code-stationary nearest-code search, full codebook per block.
// Block = 16 waves; wave w holds code tiles {2w, 2w+1} (32 codes) in
// registers forever. Grid = 256 slabs of 128 rows. x streams through LDS
// (bf16, XOR-swizzled, double-buffered, T14 load-early/write-late).
// Winners are block-local: per-phase fragments go to kall[] in LDS,
// one combine at the end, plain stores to idx_ws. One barrier per phase.
__global__ __launch_bounds__(1024, 4) void vq_search(
    const float* __restrict__ x,
    const u16* __restrict__ ehws,
    const float* __restrict__ esq1,
    u32* __restrict__ idx_ws) {
    __shared__ u16 xl[2][16 * NV];        // 16 KB: double-buffered bf16 x-tile
    __shared__ u32 kall[8][16][16];       // 8 KB: [tau][wave][row] winners

    const int t = threadIdx.x;
    const int wid = t >> 6;               // wave = 0..15 (also: staged row)
    const int lane = t & 63;
    const int lr = lane & 15;
    const int lg = lane >> 4;
    const size_t row0 = (size_t)blockIdx.x * SLABR;

    // ---- stationary B: this wave's 2 code tiles (32 codes) + their esq ----
    const u16* bb0 = ehws + (size_t)(2 * wid) * TSH + lane * 8;
    const u16* bb1 = ehws + (size_t)(2 * wid + 1) * TSH + lane * 8;
    short8 b0[8], b1[8];
#pragma unroll
    for (int ks = 0; ks < 8; ++ks) {
        b0[ks] = *(const short8*)(bb0 + ks * 512);
        b1[ks] = *(const short8*)(bb1 + ks * 512);
    }
    const float evq0 = esq1[(2 * wid) * 16 + lr];       // esq + 2.0
    const float evq1 = esq1[(2 * wid + 1) * 16 + lr];
    const u32 cid0 = (u32)((2 * wid) * 16 + lr);
    const u32 cid1 = (u32)((2 * wid + 1) * 16 + lr);

#define XLOAD(XR, TAU)                                                         \
    XR = *(const float4*)(x + (row0 + (TAU) * 16 + wid) * NV + lane * 4)
#define XWRITE(XR, BUF) do {                                                   \
        u32 lo = (u32)f2bf(XR.x) | ((u32)f2bf(XR.y) << 16);                    \
        u32 hi = (u32)f2bf(XR.z) | ((u32)f2bf(XR.w) << 16);                    \
        int byte = wid * 512 + ((lane * 8) ^ ((wid & 7) << 4));                \
        *(uint2*)((char*)&xl[BUF][0] + byte) = make_uint2(lo, hi);             \
    } while (0)

    float4 xr;
    XLOAD(xr, 0);
    XWRITE(xr, 0);
    __syncthreads();

    // ---- 8 phases over x-tiles ----
#pragma unroll 2
    for (int tau = 0; tau < 8; ++tau) {
        const int buf = tau & 1;
        if (tau < 7) XLOAD(xr, tau + 1);          // issue early (T14)

        floatx4 a0e = {0.f,0.f,0.f,0.f}, a0o = {0.f,0.f,0.f,0.f};
        floatx4 a1e = {0.f,0.f,0.f,0.f}, a1o = {0.f,0.f,0.f,0.f};
#pragma unroll
        for (int ks = 0; ks < 8; ++ks) {
            // A-frag: row lr, dims ks*32+lg*8.. ; same XOR swizzle as write
            int byte = lr * 512 + ((ks * 64 + lg * 16) ^ ((lr & 7) << 4));
            short8 a = *(const short8*)((const char*)&xl[buf][0] + byte);
            if (ks & 1) { a0o = mfma16(a, b0[ks], a0o); a1o = mfma16(a, b1[ks], a1o); }
            else        { a0e = mfma16(a, b0[ks], a0e); a1e = mfma16(a, b1[ks], a1e); }
        }
        u32 rmin[4];
#pragma unroll
        for (int j = 0; j < 4; ++j) {
            // d+2 = (esq+2) - 2*cross > 0 -> raw float bits are monotone
            float d0 = fmaf(-2.0f, a0e[j] + a0o[j], evq0);
            float d1 = fmaf(-2.0f, a1e[j] + a1o[j], evq1);
            u32 k0 = (__float_as_uint(d0) & 0xfffffe00u) | cid0;
            u32 k1 = (__float_as_uint(d1) & 0xfffffe00u) | cid1;
            rmin[j] = min(k0, k1);
        }
        // min over this wave's 16 code-lanes (low 4 lane bits)
#pragma unroll
        for (int j = 0; j < 4; ++j) {
#pragma unroll
            for (int m = 1; m <= 8; m <<= 1) {
                u32 v = (u32)__shfl_xor((int)rmin[j], m, 64);
                rmin[j] = min(rmin[j], v);
            }
        }
        if (lr == 0) {
#pragma unroll
            for (int j = 0; j < 4; ++j) kall[tau][wid][lg * 4 + j] = rmin[j];
        }

        if (tau < 7) XWRITE(xr, buf ^ 1);          // write late (T14)
        __syncthreads();
    }
#undef XLOAD
#undef XWRITE

    // ---- final combine: min across the 16 waves, plain store ----
    if (t < SLABR) {
        u32 v = 0xffffffffu;
#pragma unroll
        for (int w = 0; w < 16; ++w) v = min(v, kall[t >> 4][w][t & 15]);
        idx_ws[row0 + t] = v & 511u;
    }
}

// Kernel 2: epilogue — pure streaming (NO threadfence/election: an
// agent-scope fence per block writes back the XCD L2 and was the R11/R12
// bottleneck). Gather e[idx], straight-through out0, loss sums, histogram.
// Grid 1024 x 256: 4 waves/block, 8 rows/wave, idx prefetched, unrolled
// independent float4 streams.
__global__ __launch_bounds__(256) void vq_epi(
    const float* __restrict__ x,
    const float* __restrict__ emb,
    const u32* __restrict__ idx_ws,
    int* __restrict__ hist,
    float* __restrict__ out0,
    float* __restrict__ out1,
    float* __restrict__ out2) {
    const int t = threadIdx.x;
    const int wid = t >> 6;
    const int lane = t & 63;
    const size_t rbase = ((size_t)blockIdx.x * 4 + wid) * 8;

    int idx[8];
#pragma unroll
    for (int rr = 0; rr < 8; ++rr) idx[rr] = (int)idx_ws[rbase + rr];

    float s[8];
#pragma unroll
    for (int rr = 0; rr < 8; ++rr) {
        const size_t row = rbase + rr;
        const float4 xv = *(const float4*)(x + row * NV + lane * 4);
        const float4 ev = *(const float4*)(emb + (size_t)idx[rr] * NV + lane * 4);
        float4 o;
        o.x = (ev.x - xv.x) + xv.x;
        o.y = (ev.y - xv.y) + xv.y;
        o.z = (ev.z - xv.z) + xv.z;
        o.w = (ev.w - xv.w) + xv.w;
        *(float4*)(out0 + row * NV + lane * 4) = o;
        float d0 = xv.x - ev.x, d1 = xv.y - ev.y, d2 = xv.z - ev.z, d3 = xv.w - ev.w;
        s[rr] = d0 * d0 + d1 * d1 + d2 * d2 + d3 * d3;
    }
#pragma unroll
    for (int rr = 0; rr < 8; ++rr) {
#pragma unroll
        for (int m = 1; m <= 32; m <<= 1) s[rr] += __shfl_xor(s[rr], m, 64);
    }
    if (lane == 0) {
#pragma unroll
        for (int rr = 0; rr < 8; ++rr) {
            out1[rbase + rr] = s[rr];
            out2[rbase + rr] = s[rr];
            atomicAdd(&hist[idx[rr]], 1);   // device-scope by default
        }
    }
}

// Kernel 3: entropy of code-usage histogram (1 block; plain loads see the
// prior kernel's device-scope atomics — the proven R1-R6 pattern).
__global__ __launch_bounds__(256) void vq_entropy(const int* __restrict__ hist,
                                                  float* __restrict__ out_ent,
                                                  int n_rows) {
    __shared__ float sdata[256];
    int t = threadIdx.x;
    float local = 0.0f;
    float invn = 1.0f / (float)n_rows;
    for (int k = t; k < NK; k += 256) {
        int h = hist[k];
        if (h > 0) {
            float p = (float)h * invn;
            local += p * logf(p);
        }
    }
    sdata[t] = local;
    __syncthreads();
    for (int s = 128; s >= 1; s >>= 1) {
        if (t < s) sdata[t] += sdata[t + s];
        __syncthreads();
    }
    if (t == 0) *out_ent = -sdata[0];
}

extern "C" void kernel_launch(void* const* d_in, const int* in_sizes, int n_in,
                              void* d_out, int out_size, void* d_ws, size_t ws_size,
                              hipStream_t stream) {
    const float* x   = (const float*)d_in[0];   // (B,T,1,256) fp32
    const float* emb = (const float*)d_in[1];   // (1,512,256) fp32

    const int n_rows = in_sizes[0] / NV;        // 32768

    float* out0 = (float*)d_out;
    float* out1 = out0 + (size_t)n_rows * NV;
    float* out2 = out1 + n_rows;
    float* ent  = out2 + n_rows;

    // ws: esq+2 (2KB) | hist (2KB) | pad | idx_ws (128KB) | bf16 codebook (256KB)
    float* esq1  = (float*)d_ws;
    int* hist    = (int*)(esq1 + NK);
    u32* idx_ws  = (u32*)(hist + NK + 4);
    u16* ehws    = (u16*)(idx_ws + n_rows);

    vq_prepcvt<<<NK / 4, 256, 0, stream>>>(emb, esq1, ehws, hist);
    vq_search<<<n_rows / SLABR, 1024, 0, stream>>>(x, ehws, esq1, idx_ws);
    vq_epi<<<n_rows / 32, 256, 0, stream>>>(x, emb, idx_ws, hist,
                                            out0, out1, out2);
    vq_entropy<<<1, 256, 0, stream>>>(hist, ent, n_rows);
}

// Round 14
// 45.210 us; speedup vs baseline: 2.5066x; 1.2093x over previous
//
#include <hip/hip_runtime.h>
#include <math.h>

// Problem constants: B*T = 32768 rows, C=1, V=256, K=512 codes.
#define NV 256
#define NK 512
#define TSH 4096      // shorts per 16-code tile (16 codes * 256 dims, bf16)
#define SLABR 128     // rows per search block (8 x-tiles of 16)

typedef unsigned short u16;
typedef unsigned int u32;
using short8  = __attribute__((ext_vector_type(8))) short;
using floatx4 = __attribute__((ext_vector_type(4))) float;

// fp32 -> bf16 round-to-nearest-even.
__device__ __forceinline__ u16 f2bf(float f) {
    unsigned int u = __float_as_uint(f);
    u += 0x7fffu + ((u >> 16) & 1u);
    return (u16)(u >> 16);
}
__device__ __forceinline__ floatx4 mfma16(short8 a, short8 b, floatx4 c) {
    return __builtin_amdgcn_mfma_f32_16x16x32_bf16(a, b, c, 0, 0, 0);
}

// Kernel 0: per-code esq(+2.0 bias: distance keys provably positive), bf16
// codebook packed in MFMA order shorts[tile][kc][code][8]; zero hist.
__global__ __launch_bounds__(256) void vq_prepcvt(const float* __restrict__ emb,
                                                  float* __restrict__ esq1,
                                                  u16* __restrict__ ehws,
                                                  int* __restrict__ hist) {
    const int t = threadIdx.x;
    const int lane = t & 63;
    const int code = blockIdx.x * 4 + (t >> 6);   // one wave per code
    const int nt = code >> 4, c = code & 15;
    const float4 v = *(const float4*)(emb + (size_t)code * NV + lane * 4);
    ushort4 h;
    h.x = f2bf(v.x);
    h.y = f2bf(v.y);
    h.z = f2bf(v.z);
    h.w = f2bf(v.w);
    // dim base = lane*4 -> kchunk8 = lane>>1, j0 = (lane&1)*4
    const size_t base = (size_t)nt * TSH + (size_t)(lane >> 1) * 128 + c * 8 + (lane & 1) * 4;
    *(ushort4*)(ehws + base) = h;
    float s = v.x * v.x + v.y * v.y + v.z * v.z + v.w * v.w;
#pragma unroll
    for (int m = 1; m <= 32; m <<= 1) s += __shfl_xor(s, m, 64);
    if (lane == 0) esq1[code] = s + 2.0f;
    const int g = blockIdx.x * 256 + t;
    if (g < NK) hist[g] = 0;
}

// Kernel 1 (fused search + epilogue): code-stationary nearest-code search,
// full codebook per block, then in-block epilogue on L2-warm data.
// Block = 16 waves; wave w holds code tiles {2w, 2w+1} (32 codes) in
// registers forever. Grid = 256 slabs of 128 rows. x streams through LDS
// (bf16, XOR-swizzled, double-buffered, T14 load-early/write-late);
// winners block-local (kall in LDS, one combine, NO global fences);
// epilogue: 8 rows/wave, exact fp32 x (L2 hit), e gather (L2), out0/1/2.
__global__ __launch_bounds__(1024, 4) void vq_main(
    const float* __restrict__ x,
    const float* __restrict__ emb,
    const u16* __restrict__ ehws,
    const float* __restrict__ esq1,
    int* __restrict__ hist,
    float* __restrict__ out0,
    float* __restrict__ out1,
    float* __restrict__ out2) {
    __shared__ u16 xl[2][16 * NV];        // 16 KB: double-buffered bf16 x-tile
    __shared__ u32 kall[8][16][16];       // 8 KB: [tau][wave][row] winners
    __shared__ u32 idx_lds[SLABR];        // 512 B: per-row winning code

    const int t = threadIdx.x;
    const int wid = t >> 6;               // wave = 0..15 (also: staged row)
    const int lane = t & 63;
    const int lr = lane & 15;
    const int lg = lane >> 4;
    const size_t row0 = (size_t)blockIdx.x * SLABR;

    // ---- stationary B: this wave's 2 code tiles (32 codes) + their esq ----
    const u16* bb0 = ehws + (size_t)(2 * wid) * TSH + lane * 8;
    const u16* bb1 = ehws + (size_t)(2 * wid + 1) * TSH + lane * 8;
    short8 b0[8], b1[8];
#pragma unroll
    for (int ks = 0; ks < 8; ++ks) {
        b0[ks] = *(const short8*)(bb0 + ks * 512);
        b1[ks] = *(const short8*)(bb1 + ks * 512);
    }
    const float evq0 = esq1[(2 * wid) * 16 + lr];       // esq + 2.0
    const float evq1 = esq1[(2 * wid + 1) * 16 + lr];
    const u32 cid0 = (u32)((2 * wid) * 16 + lr);
    const u32 cid1 = (u32)((2 * wid + 1) * 16 + lr);

#define XLOAD(XR, TAU)                                                         \
    XR = *(const float4*)(x + (row0 + (TAU) * 16 + wid) * NV + lane * 4)
#define XWRITE(XR, BUF) do {                                                   \
        u32 lo = (u32)f2bf(XR.x) | ((u32)f2bf(XR.y) << 16);                    \
        u32 hi = (u32)f2bf(XR.z) | ((u32)f2bf(XR.w) << 16);                    \
        int byte = wid * 512 + ((lane * 8) ^ ((wid & 7) << 4));                \
        *(uint2*)((char*)&xl[BUF][0] + byte) = make_uint2(lo, hi);             \
    } while (0)

    float4 xr;
    XLOAD(xr, 0);
    XWRITE(xr, 0);
    __syncthreads();

    // ---- 8 phases over x-tiles ----
#pragma unroll 2
    for (int tau = 0; tau < 8; ++tau) {
        const int buf = tau & 1;
        if (tau < 7) XLOAD(xr, tau + 1);          // issue early (T14)

        floatx4 a0e = {0.f,0.f,0.f,0.f}, a0o = {0.f,0.f,0.f,0.f};
        floatx4 a1e = {0.f,0.f,0.f,0.f}, a1o = {0.f,0.f,0.f,0.f};
#pragma unroll
        for (int ks = 0; ks < 8; ++ks) {
            // A-frag: row lr, dims ks*32+lg*8.. ; same XOR swizzle as write
            int byte = lr * 512 + ((ks * 64 + lg * 16) ^ ((lr & 7) << 4));
            short8 a = *(const short8*)((const char*)&xl[buf][0] + byte);
            if (ks & 1) { a0o = mfma16(a, b0[ks], a0o); a1o = mfma16(a, b1[ks], a1o); }
            else        { a0e = mfma16(a, b0[ks], a0e); a1e = mfma16(a, b1[ks], a1e); }
        }
        u32 rmin[4];
#pragma unroll
        for (int j = 0; j < 4; ++j) {
            // d+2 = (esq+2) - 2*cross > 0 -> raw float bits are monotone
            float d0 = fmaf(-2.0f, a0e[j] + a0o[j], evq0);
            float d1 = fmaf(-2.0f, a1e[j] + a1o[j], evq1);
            u32 k0 = (__float_as_uint(d0) & 0xfffffe00u) | cid0;
            u32 k1 = (__float_as_uint(d1) & 0xfffffe00u) | cid1;
            rmin[j] = min(k0, k1);
        }
        // min over this wave's 16 code-lanes (low 4 lane bits)
#pragma unroll
        for (int j = 0; j < 4; ++j) {
#pragma unroll
            for (int m = 1; m <= 8; m <<= 1) {
                u32 v = (u32)__shfl_xor((int)rmin[j], m, 64);
                rmin[j] = min(rmin[j], v);
            }
        }
        if (lr == 0) {
#pragma unroll
            for (int j = 0; j < 4; ++j) kall[tau][wid][lg * 4 + j] = rmin[j];
        }

        if (tau < 7) XWRITE(xr, buf ^ 1);          // write late (T14)
        __syncthreads();
    }
#undef XLOAD
#undef XWRITE

    // ---- final combine: min across the 16 waves -> idx_lds + hist ----
    if (t < SLABR) {
        u32 v = 0xffffffffu;
#pragma unroll
        for (int w = 0; w < 16; ++w) v = min(v, kall[t >> 4][w][t & 15]);
        const int idx = (int)(v & 511u);
        idx_lds[t] = (u32)idx;
        atomicAdd(&hist[idx], 1);       // device-scope by default
    }
    __syncthreads();

    // ---- fused epilogue: 8 rows/wave in two 4-row batches (VGPR cap 128) ----
    const size_t rb = row0 + (size_t)wid * 8;
#pragma unroll
    for (int batch = 0; batch < 2; ++batch) {
        const int r0 = batch * 4;
        int idx4[4];
#pragma unroll
        for (int rr = 0; rr < 4; ++rr) idx4[rr] = (int)idx_lds[wid * 8 + r0 + rr];
        float4 xv[4], ev[4];
#pragma unroll
        for (int rr = 0; rr < 4; ++rr) {
            const size_t row = rb + r0 + rr;
            xv[rr] = *(const float4*)(x + row * NV + lane * 4);
            ev[rr] = *(const float4*)(emb + (size_t)idx4[rr] * NV + lane * 4);
        }
        float s[4];
#pragma unroll
        for (int rr = 0; rr < 4; ++rr) {
            const size_t row = rb + r0 + rr;
            float4 o;
            o.x = (ev[rr].x - xv[rr].x) + xv[rr].x;
            o.y = (ev[rr].y - xv[rr].y) + xv[rr].y;
            o.z = (ev[rr].z - xv[rr].z) + xv[rr].z;
            o.w = (ev[rr].w - xv[rr].w) + xv[rr].w;
            *(float4*)(out0 + row * NV + lane * 4) = o;
            float d0 = xv[rr].x - ev[rr].x, d1 = xv[rr].y - ev[rr].y;
            float d2 = xv[rr].z - ev[rr].z, d3 = xv[rr].w - ev[rr].w;
            s[rr] = d0 * d0 + d1 * d1 + d2 * d2 + d3 * d3;
        }
#pragma unroll
        for (int rr = 0; rr < 4; ++rr) {
#pragma unroll
            for (int m = 1; m <= 32; m <<= 1) s[rr] += __shfl_xor(s[rr], m, 64);
        }
        if (lane == 0) {
#pragma unroll
            for (int rr = 0; rr < 4; ++rr) {
                out1[rb + r0 + rr] = s[rr];
                out2[rb + r0 + rr] = s[rr];
            }
        }
    }
}

// Kernel 2: entropy of code-usage histogram (1 block; plain loads see the
// prior kernel's device-scope atomics — proven pattern).
__global__ __launch_bounds__(256) void vq_entropy(const int* __restrict__ hist,
                                                  float* __restrict__ out_ent,
                                                  int n_rows) {
    __shared__ float sdata[256];
    int t = threadIdx.x;
    float local = 0.0f;
    float invn = 1.0f / (float)n_rows;
    for (int k = t; k < NK; k += 256) {
        int h = hist[k];
        if (h > 0) {
            float p = (float)h * invn;
            local += p * logf(p);
        }
    }
    sdata[t] = local;
    __syncthreads();
    for (int s = 128; s >= 1; s >>= 1) {
        if (t < s) sdata[t] += sdata[t + s];
        __syncthreads();
    }
    if (t == 0) *out_ent = -sdata[0];
}

extern "C" void kernel_launch(void* const* d_in, const int* in_sizes, int n_in,
                              void* d_out, int out_size, void* d_ws, size_t ws_size,
                              hipStream_t stream) {
    const float* x   = (const float*)d_in[0];   // (B,T,1,256) fp32
    const float* emb = (const float*)d_in[1];   // (1,512,256) fp32

    const int n_rows = in_sizes[0] / NV;        // 32768

    float* out0 = (float*)d_out;
    float* out1 = out0 + (size_t)n_rows * NV;
    float* out2 = out1 + n_rows;
    float* ent  = out2 + n_rows;

    // ws: esq+2 (2KB) | hist (2KB) | pad | bf16 codebook (256KB)
    float* esq1  = (float*)d_ws;
    int* hist    = (int*)(esq1 + NK);
    u16* ehws    = (u16*)(hist + NK + 4);

    vq_prepcvt<<<NK / 4, 256, 0, stream>>>(emb, esq1, ehws, hist);
    vq_main<<<n_rows / SLABR, 1024, 0, stream>>>(x, emb, ehws, esq1, hist,
                                                 out0, out1, out2);
    vq_entropy<<<1, 256, 0, stream>>>(hist, ent, n_rows);
}